// Round 6
// baseline (1172.362 us; speedup 1.0000x reference)
//
#include <hip/hip_runtime.h>
#include <hip/hip_bf16.h>

#define N_TOK 16384
#define H_DIM 2048
#define NE 8
#define CHUNK 2048
#define IPE 1024
#define F2 2048

typedef __bf16 bf16;
typedef bf16 bf16x8 __attribute__((ext_vector_type(8)));
typedef float f32x4 __attribute__((ext_vector_type(4)));

typedef __attribute__((address_space(1))) void gvoid;
typedef __attribute__((address_space(3))) void svoid;

__device__ __forceinline__ void gload_lds16(const void* g, void* l) {
  __builtin_amdgcn_global_load_lds((gvoid*)g, (svoid*)l, 16, 0, 0);
}
__device__ __forceinline__ f32x4 MF(bf16x8 a, bf16x8 b, f32x4 c) {
  return __builtin_amdgcn_mfma_f32_16x16x32_bf16(a, b, c, 0, 0, 0);
}

#define BAR() __builtin_amdgcn_s_barrier()
#define LGKM0() asm volatile("s_waitcnt lgkmcnt(0)" ::: "memory")
#define LGKM8() asm volatile("s_waitcnt lgkmcnt(8)" ::: "memory")
#define VM0() asm volatile("s_waitcnt vmcnt(0)" ::: "memory")
#define PRIO(x) __builtin_amdgcn_s_setprio(x)
#define SCHED0() __builtin_amdgcn_sched_barrier(0)

// ===========================================================================
// Fused MoE MLP, 2 kernels. 256x256x64 tiles, 8 waves, R5 barrier skeleton.
// LDS (128 KiB): buf*65536 + {A:0, B:32768} + half*16384; row stride 128 B;
// swizzle byte ^= ((row&7)<<4) on ds_write and ds_read (both sides).
//
// k_mlp1: act[c][f'] = silu/up( gather(hidden)[c][:] x w1 ), fp32 sources
//   converted in staging. A rows gathered via sort_idx. B via column loads
//   with gate/up 16-col interleave folded into the source-column map.
// k_mlp2: out[sidx[c]][h] = act[c][:] x w2. A bf16 via global_load_lds,
//   B fp32 column loads.
//
// Staging ledger (per tile t, bufs alternate cur=t&1):
//   A(t+1): issued t-1.P3, cvt+ds_write at t.P1 into buf[nxt]
//           (buf[nxt].A last read t-1.P2; readers t+1.P0/P2)
//   B(t+1): issued t.P2,  cvt+ds_write at t.P3 into buf[nxt]
//           (buf[nxt].B last read t-1.P1; readers t+1.P0/P1)
//   Writes drained by per-wave LGKM0 before the phase's trailing BAR.
// ===========================================================================
__global__ __launch_bounds__(512, 2) void k_mlp1(
    const float* __restrict__ hidden, const int* __restrict__ sidx,
    const float* __restrict__ w1, bf16* __restrict__ act) {
  extern __shared__ char smem[];
  const int tid = threadIdx.x, lane = tid & 63, wv = tid >> 6;
  const int wm = wv >> 2, wn = wv & 3;
  constexpr int NT = H_DIM / 64;  // 32

  const int orig = blockIdx.x;
  const int e = orig >> 6, bm = (orig >> 3) & 7, bn = orig & 7;

  // ---- A staging (gathered fp32 rows): thread owns row mA, k-half khalf ----
  const int mA = tid >> 1;
  const int khalf = (tid & 1) * 32;  // float offset within 64-wide K tile
  const int srcTok = sidx[e * CHUNK + bm * 256 + mA];
  const float* Arow = hidden + (size_t)srcTok * H_DIM + khalf;
  const int AwOff = ((mA >> 7) << 14) + ((mA & 127) << 7);
  const int swzA = (mA & 7) << 4;

  // ---- B staging (column loads): thread owns LDS row n', k-half khalf ----
  const int np = tid >> 1;
  const int fcol = bn * 128 + ((np >> 6) & 3) * 32 + ((np >> 5) & 1) * 16 +
                   (np & 15) + ((np >> 4) & 1) * 1024;
  const float* Bcol = w1 + (size_t)e * H_DIM * F2 + fcol;
  const int BwOff = 32768 + ((np >> 7) << 14) + ((np & 127) << 7);
  const int swzB = (np & 7) << 4;

  // ---- fragment-read constants ----
  const int rA = lane & 15;
  const int swzr = (rA & 7) << 4;
  const int cb = (lane >> 4) * 16;

  f32x4 acc[8][4] = {};
  float4 aload[8];
  float bl[32];

  auto issueA = [&](int kbase) {
#pragma unroll
    for (int j = 0; j < 8; ++j)
      aload[j] = *(const float4*)(Arow + kbase + j * 4);
  };
  auto writeA = [&](int buf) {
#pragma unroll
    for (int w = 0; w < 4; ++w) {
      float4 u0 = aload[2 * w], u1 = aload[2 * w + 1];
      bf16x8 tv;
      tv[0] = (bf16)u0.x; tv[1] = (bf16)u0.y; tv[2] = (bf16)u0.z; tv[3] = (bf16)u0.w;
      tv[4] = (bf16)u1.x; tv[5] = (bf16)u1.y; tv[6] = (bf16)u1.z; tv[7] = (bf16)u1.w;
      *(bf16x8*)(smem + buf * 65536 + AwOff + ((khalf * 2 + w * 16) ^ swzA)) = tv;
    }
  };
  auto issueB = [&](int kbase) {
    const float* bp = Bcol + (size_t)(kbase + khalf) * F2;
#pragma unroll
    for (int j = 0; j < 32; ++j) bl[j] = bp[(size_t)j * F2];
  };
  auto writeB = [&](int buf) {
#pragma unroll
    for (int w = 0; w < 4; ++w) {
      bf16x8 tv;
#pragma unroll
      for (int i = 0; i < 8; ++i) tv[i] = (bf16)bl[w * 8 + i];
      *(bf16x8*)(smem + buf * 65536 + BwOff + ((khalf * 2 + w * 16) ^ swzB)) = tv;
    }
  };
  auto ldA = [&](int buf, int mi, int ks) {
    int lin = ((mi * 16 + rA) << 7) + ks * 64 + cb;
    return *(const bf16x8*)(smem + buf * 65536 + wm * 16384 + (lin ^ swzr));
  };
  auto ldB = [&](int buf, int ni, int ks) {
    int lin = (((wn & 1) * 64 + ni * 16 + rA) << 7) + ks * 64 + cb;
    return *(const bf16x8*)(smem + buf * 65536 + 32768 + (wn >> 1) * 16384 + (lin ^ swzr));
  };

  // ---- prologue: tile0 staged+written; tile1 A issued ----
  issueA(0);
  issueB(0);
  writeA(0);
  writeB(0);
  issueA(64);  // tile 1
  LGKM0();
  BAR();

  auto ktile = [&](int t, int cur) {
    const int nxt = cur ^ 1;
    bf16x8 AA[4][2], B0[2][2], B1[2][2];
    // ---- P0: frags A0(8)+B0(4) ----
#pragma unroll
    for (int mi = 0; mi < 4; ++mi) {
      AA[mi][0] = ldA(cur, mi, 0);
      AA[mi][1] = ldA(cur, mi, 1);
    }
#pragma unroll
    for (int ni = 0; ni < 2; ++ni) {
      B0[ni][0] = ldB(cur, ni, 0);
      B0[ni][1] = ldB(cur, ni, 1);
    }
    LGKM8();
    BAR();
    LGKM0();
    SCHED0();
    PRIO(1);
#pragma unroll
    for (int mi = 0; mi < 4; ++mi)
#pragma unroll
      for (int ni = 0; ni < 2; ++ni) {
        acc[mi][ni] = MF(AA[mi][0], B0[ni][0], acc[mi][ni]);
        acc[mi][ni] = MF(AA[mi][1], B0[ni][1], acc[mi][ni]);
      }
    PRIO(0);
    BAR();
    // ---- P1: frags B1(4); write A(t+1) ----
#pragma unroll
    for (int ni = 0; ni < 2; ++ni) {
      B1[ni][0] = ldB(cur, 2 + ni, 0);
      B1[ni][1] = ldB(cur, 2 + ni, 1);
    }
    if (t + 1 < NT) writeA(nxt);
    BAR();
    LGKM0();
    SCHED0();
    PRIO(1);
#pragma unroll
    for (int mi = 0; mi < 4; ++mi)
#pragma unroll
      for (int ni = 0; ni < 2; ++ni) {
        acc[mi][2 + ni] = MF(AA[mi][0], B1[ni][0], acc[mi][2 + ni]);
        acc[mi][2 + ni] = MF(AA[mi][1], B1[ni][1], acc[mi][2 + ni]);
      }
    PRIO(0);
    BAR();
    // ---- P2: frags A1(8); issue B(t+1) ----
#pragma unroll
    for (int mi = 0; mi < 4; ++mi) {
      AA[mi][0] = ldA(cur, 4 + mi, 0);
      AA[mi][1] = ldA(cur, 4 + mi, 1);
    }
    if (t + 1 < NT) issueB((t + 1) * 64);
    BAR();
    LGKM0();
    SCHED0();
    PRIO(1);
#pragma unroll
    for (int mi = 0; mi < 4; ++mi)
#pragma unroll
      for (int ni = 0; ni < 2; ++ni) {
        acc[4 + mi][ni] = MF(AA[mi][0], B0[ni][0], acc[4 + mi][ni]);
        acc[4 + mi][ni] = MF(AA[mi][1], B0[ni][1], acc[4 + mi][ni]);
      }
    PRIO(0);
    BAR();
    // ---- P3: write B(t+1); issue A(t+2) ----
    if (t + 1 < NT) writeB(nxt);
    if (t + 2 < NT) issueA((t + 2) * 64);
    LGKM0();
    BAR();
    PRIO(1);
#pragma unroll
    for (int mi = 0; mi < 4; ++mi)
#pragma unroll
      for (int ni = 0; ni < 2; ++ni) {
        acc[4 + mi][2 + ni] = MF(AA[mi][0], B1[ni][0], acc[4 + mi][2 + ni]);
        acc[4 + mi][2 + ni] = MF(AA[mi][1], B1[ni][1], acc[4 + mi][2 + ni]);
      }
    PRIO(0);
    BAR();
  };

  for (int tt = 0; tt < NT; tt += 2) {
    ktile(tt, 0);
    ktile(tt + 1, 1);
  }

  // ---- epilogue: silu(gate)*up, fragment pairs (2p,2p+1)=(gate,up) ----
  bf16* actp = act + ((size_t)e * CHUNK + bm * 256 + wm * 128) * IPE;
  const int r0 = (lane >> 4) * 4;
  const int c0 = bn * 128 + wn * 32 + (lane & 15);
#pragma unroll
  for (int mi = 0; mi < 8; ++mi)
#pragma unroll
    for (int p = 0; p < 2; ++p) {
      f32x4 g = acc[mi][2 * p], u = acc[mi][2 * p + 1];
#pragma unroll
      for (int r = 0; r < 4; ++r) {
        float gv = g[r];
        float a = gv / (1.f + __expf(-gv)) * u[r];
        actp[(size_t)(mi * 16 + r0 + r) * IPE + c0 + p * 16] = (bf16)a;
      }
    }
}

// ===========================================================================
__global__ __launch_bounds__(512, 2) void k_mlp2(
    const bf16* __restrict__ act, const float* __restrict__ w2,
    const int* __restrict__ sidx, float* __restrict__ out) {
  extern __shared__ char smem[];
  const int tid = threadIdx.x, lane = tid & 63, wv = tid >> 6;
  const int wm = wv >> 2, wn = wv & 3;
  constexpr int NT = IPE / 64;  // 16

  const int orig = blockIdx.x;
  const int e = orig >> 6, bm = (orig >> 3) & 7, bn = orig & 7;

  const char* Ab = (const char*)(act + ((size_t)e * CHUNK + bm * 256) * IPE);

  // pre-swizzled source coords for A gload_lds (LDS dest linear)
  const int L0 = wv * 1024 + lane * 16;
  const int lin0 = L0 ^ (((L0 >> 7) & 7) << 4);
  const int srow0 = lin0 >> 7, scolb = lin0 & 127;

  // ---- B staging: thread owns LDS row n' = output col bn*256+n' ----
  const int np = tid >> 1;
  const int khalf = (tid & 1) * 32;
  const float* Bcol = w2 + (size_t)e * IPE * H_DIM + bn * 256 + np;
  const int BwOff = 32768 + ((np >> 7) << 14) + ((np & 127) << 7);
  const int swzB = (np & 7) << 4;

  const int rA = lane & 15;
  const int swzr = (rA & 7) << 4;
  const int cb = (lane >> 4) * 16;

  f32x4 acc[8][4] = {};
  float bl[32];

  auto stageA = [&](int buf, int kt) {
#pragma unroll
    for (int half = 0; half < 2; ++half) {
      char* ld = smem + buf * 65536 + half * 16384 + wv * 1024;
      size_t rb = (size_t)(half * 128 + srow0) * (IPE * 2) + (size_t)kt * 128 + scolb;
      gload_lds16(Ab + rb, ld);
      gload_lds16(Ab + rb + (size_t)64 * (IPE * 2), ld + 8192);
    }
  };
  auto issueB = [&](int kbase) {
    const float* bp = Bcol + (size_t)(kbase + khalf) * H_DIM;
#pragma unroll
    for (int j = 0; j < 32; ++j) bl[j] = bp[(size_t)j * H_DIM];
  };
  auto writeB = [&](int buf) {
#pragma unroll
    for (int w = 0; w < 4; ++w) {
      bf16x8 tv;
#pragma unroll
      for (int i = 0; i < 8; ++i) tv[i] = (bf16)bl[w * 8 + i];
      *(bf16x8*)(smem + buf * 65536 + BwOff + ((khalf * 2 + w * 16) ^ swzB)) = tv;
    }
  };
  auto ldA = [&](int buf, int mi, int ks) {
    int lin = ((mi * 16 + rA) << 7) + ks * 64 + cb;
    return *(const bf16x8*)(smem + buf * 65536 + wm * 16384 + (lin ^ swzr));
  };
  auto ldB = [&](int buf, int ni, int ks) {
    int lin = (((wn & 1) * 64 + ni * 16 + rA) << 7) + ks * 64 + cb;
    return *(const bf16x8*)(smem + buf * 65536 + 32768 + (wn >> 1) * 16384 + (lin ^ swzr));
  };

  // ---- prologue ----
  stageA(0, 0);
  issueB(0);
  writeB(0);
  VM0();   // drain A gload_lds (compiler's counted wait for bl may not cover)
  LGKM0();
  BAR();

  auto ktile = [&](int t, int cur) {
    const int nxt = cur ^ 1;
    bf16x8 AA[4][2], B0[2][2], B1[2][2];
    // ---- P0: frags A0+B0; stage A(t+1) via gload_lds ----
#pragma unroll
    for (int mi = 0; mi < 4; ++mi) {
      AA[mi][0] = ldA(cur, mi, 0);
      AA[mi][1] = ldA(cur, mi, 1);
    }
#pragma unroll
    for (int ni = 0; ni < 2; ++ni) {
      B0[ni][0] = ldB(cur, ni, 0);
      B0[ni][1] = ldB(cur, ni, 1);
    }
    if (t + 1 < NT) stageA(nxt, t + 1);
    LGKM8();
    BAR();
    LGKM0();
    SCHED0();
    PRIO(1);
#pragma unroll
    for (int mi = 0; mi < 4; ++mi)
#pragma unroll
      for (int ni = 0; ni < 2; ++ni) {
        acc[mi][ni] = MF(AA[mi][0], B0[ni][0], acc[mi][ni]);
        acc[mi][ni] = MF(AA[mi][1], B0[ni][1], acc[mi][ni]);
      }
    PRIO(0);
    BAR();
    // ---- P1: frags B1 ----
#pragma unroll
    for (int ni = 0; ni < 2; ++ni) {
      B1[ni][0] = ldB(cur, 2 + ni, 0);
      B1[ni][1] = ldB(cur, 2 + ni, 1);
    }
    BAR();
    LGKM0();
    SCHED0();
    PRIO(1);
#pragma unroll
    for (int mi = 0; mi < 4; ++mi)
#pragma unroll
      for (int ni = 0; ni < 2; ++ni) {
        acc[mi][2 + ni] = MF(AA[mi][0], B1[ni][0], acc[mi][2 + ni]);
        acc[mi][2 + ni] = MF(AA[mi][1], B1[ni][1], acc[mi][2 + ni]);
      }
    PRIO(0);
    BAR();
    // ---- P2: frags A1; issue B(t+1) ----
#pragma unroll
    for (int mi = 0; mi < 4; ++mi) {
      AA[mi][0] = ldA(cur, 4 + mi, 0);
      AA[mi][1] = ldA(cur, 4 + mi, 1);
    }
    if (t + 1 < NT) issueB((t + 1) * 64);
    BAR();
    LGKM0();
    SCHED0();
    PRIO(1);
#pragma unroll
    for (int mi = 0; mi < 4; ++mi)
#pragma unroll
      for (int ni = 0; ni < 2; ++ni) {
        acc[4 + mi][ni] = MF(AA[mi][0], B0[ni][0], acc[4 + mi][ni]);
        acc[4 + mi][ni] = MF(AA[mi][1], B0[ni][1], acc[4 + mi][ni]);
      }
    PRIO(0);
    BAR();
    // ---- P3: write B(t+1); drain A gloads; MFMA q3 ----
    if (t + 1 < NT) {
      writeB(nxt);
      VM0();
    }
    LGKM0();
    BAR();
    PRIO(1);
#pragma unroll
    for (int mi = 0; mi < 4; ++mi)
#pragma unroll
      for (int ni = 0; ni < 2; ++ni) {
        acc[4 + mi][2 + ni] = MF(AA[mi][0], B1[ni][0], acc[4 + mi][2 + ni]);
        acc[4 + mi][2 + ni] = MF(AA[mi][1], B1[ni][1], acc[4 + mi][2 + ni]);
      }
    PRIO(0);
    BAR();
  };

  for (int tt = 0; tt < NT; tt += 2) {
    ktile(tt, 0);
    ktile(tt + 1, 1);
  }

  // ---- epilogue: scatter fp32 rows via sidx ----
  const int* sp = sidx + e * CHUNK + bm * 256 + wm * 128;
  const int r0 = (lane >> 4) * 4;
  const int c0 = bn * 256 + wn * 64 + (lane & 15);
#pragma unroll
  for (int mi = 0; mi < 8; ++mi)
#pragma unroll
    for (int r = 0; r < 4; ++r) {
      int dst = sp[mi * 16 + r0 + r];
      float* op = out + (size_t)dst * H_DIM + c0;
#pragma unroll
      for (int ni = 0; ni < 4; ++ni) op[ni * 16] = acc[mi][ni][r];
    }
}

// ---------------------------------------------------------------------------
extern "C" void kernel_launch(void* const* d_in, const int* in_sizes, int n_in,
                              void* d_out, int out_size, void* d_ws, size_t ws_size,
                              hipStream_t stream) {
  const float* hidden = (const float*)d_in[0];
  const int* sidx = (const int*)d_in[1];
  const float* w1 = (const float*)d_in[2];
  const float* w2 = (const float*)d_in[3];
  float* out = (float*)d_out;

  bf16* act = (bf16*)d_ws;  // 16384*1024*2 = 32 MiB

  hipFuncSetAttribute((const void*)k_mlp1,
                      hipFuncAttributeMaxDynamicSharedMemorySize, 131072);
  hipFuncSetAttribute((const void*)k_mlp2,
                      hipFuncAttributeMaxDynamicSharedMemorySize, 131072);

  k_mlp1<<<dim3(512), 512, 131072, stream>>>(hidden, sidx, w1, act);
  k_mlp2<<<dim3(512), 512, 131072, stream>>>(act, w2, sidx, out);
}

// Round 7
// 425.577 us; speedup vs baseline: 2.7548x; 2.7548x over previous
//
#include <hip/hip_runtime.h>
#include <hip/hip_bf16.h>

#define N_TOK 16384
#define H_DIM 2048
#define NE 8
#define CHUNK 2048
#define IPE 1024
#define F2 2048

typedef __bf16 bf16;
typedef bf16 bf16x8 __attribute__((ext_vector_type(8)));
typedef float f32x4 __attribute__((ext_vector_type(4)));

typedef __attribute__((address_space(1))) void gvoid;
typedef __attribute__((address_space(3))) void svoid;

__device__ __forceinline__ void gload_lds16(const void* g, void* l) {
  __builtin_amdgcn_global_load_lds((gvoid*)g, (svoid*)l, 16, 0, 0);
}
__device__ __forceinline__ f32x4 MF(bf16x8 a, bf16x8 b, f32x4 c) {
  return __builtin_amdgcn_mfma_f32_16x16x32_bf16(a, b, c, 0, 0, 0);
}

#define BAR() __builtin_amdgcn_s_barrier()
#define LGKM0() asm volatile("s_waitcnt lgkmcnt(0)" ::: "memory")
#define LGKM8() asm volatile("s_waitcnt lgkmcnt(8)" ::: "memory")
#define VM6() asm volatile("s_waitcnt vmcnt(6)" ::: "memory")
#define VM0() asm volatile("s_waitcnt vmcnt(0)" ::: "memory")
#define PRIO(x) __builtin_amdgcn_s_setprio(x)
#define SCHED0() __builtin_amdgcn_sched_barrier(0)

// ---------------------------------------------------------------------------
// Transpose kernels (load phase as proven R2-R5; store phase widened to
// bf16x8 16B stores via LDS column reads).
// ---------------------------------------------------------------------------
__global__ __launch_bounds__(256) void k_tr_w1(const float* __restrict__ in,
                                               bf16* __restrict__ out) {
  int e = blockIdx.z;
  int fB = blockIdx.x;
  int hB = blockIdx.y;
  __shared__ bf16 lds[64][68];
  int tx = threadIdx.x & 63;
  int ty = threadIdx.x >> 6;
  const float* ip = in + ((size_t)e * H_DIM + hB * 64) * F2;
  int scol = (tx < 32) ? (fB * 32 + tx) : (1024 + fB * 32 + (tx - 32));
#pragma unroll
  for (int p = 0; p < 16; ++p) {
    int hl = p * 4 + ty;
    lds[hl][tx] = (bf16)ip[(size_t)hl * F2 + scol];
  }
  __syncthreads();
  // store: thread owns out row f'=fl, 16 h-cols
  int fl = threadIdx.x >> 2, hseg = (threadIdx.x & 3) * 16;
  int g = fl >> 4, w = fl & 15;
  int lcol = ((g >> 1) << 4) + w + ((g & 1) << 5);
  bf16 v[16];
#pragma unroll
  for (int j = 0; j < 16; ++j) v[j] = lds[hseg + j][lcol];
  bf16* op = out + ((size_t)e * F2 + fB * 64 + fl) * H_DIM + hB * 64 + hseg;
  *(bf16x8*)op = *(bf16x8*)&v[0];
  *(bf16x8*)(op + 8) = *(bf16x8*)&v[8];
}

__global__ __launch_bounds__(256) void k_tr_w2(const float* __restrict__ in,
                                               bf16* __restrict__ out) {
  int e = blockIdx.z;
  int hB = blockIdx.x;
  int iB = blockIdx.y;
  __shared__ bf16 lds[64][68];
  int tx = threadIdx.x & 63;
  int ty = threadIdx.x >> 6;
  const float* ip = in + (size_t)e * IPE * H_DIM + (size_t)iB * 64 * H_DIM + hB * 64;
#pragma unroll
  for (int p = 0; p < 16; ++p) {
    int il = p * 4 + ty;
    lds[il][tx] = (bf16)ip[(size_t)il * H_DIM + tx];
  }
  __syncthreads();
  int hl = threadIdx.x >> 2, iseg = (threadIdx.x & 3) * 16;
  bf16 v[16];
#pragma unroll
  for (int j = 0; j < 16; ++j) v[j] = lds[iseg + j][hl];
  bf16* op = out + ((size_t)e * H_DIM + hB * 64 + hl) * IPE + iB * 64 + iseg;
  *(bf16x8*)op = *(bf16x8*)&v[0];
  *(bf16x8*)(op + 8) = *(bf16x8*)&v[8];
}

// ---------------------------------------------------------------------------
// GEMM1 with fused gather: A = hidden rows via sort_idx, reg-staged
// (coalesced 32B/lane row reads -> cvt -> swizzled ds_write_b128);
// B = w1t bf16 via gload_lds (R5 path). R5 quadrant phases.
//
// vmcnt ledger: A-h0 issued t.P0; writeA_h0 at t.P2 (compiler waits on al
// regs -> in-order drains older B(t+1) gload_lds); A-h1 issued t.P2 after
// the write, written t.P3 (drains again); B(t+2) issued t.P3 AFTER writeA
// -> stays in flight across barrier. Entering t+1: only B(t+2) outstanding,
// B(t+1) proven landed. LDS write-region safety: buf[nxt].A last read at
// (t-1).P0/P2, written t.P2/P3; buf[cur].B last read t.P1, B(t+2) issued
// t.P3. All waves separated by the phase barriers.
// ---------------------------------------------------------------------------
__global__ __launch_bounds__(512, 2) void k_gemm1f(
    const float* __restrict__ hidden, const int* __restrict__ sidx,
    const bf16* __restrict__ W, bf16* __restrict__ act) {
  extern __shared__ char smem[];
  const int tid = threadIdx.x, lane = tid & 63, wv = tid >> 6;
  const int wm = wv >> 2, wn = wv & 3;
  constexpr int KDIM = H_DIM;
  constexpr int NT = KDIM / 64;  // 32

  int swzwg = (blockIdx.x & 7) * (gridDim.x >> 3) + (blockIdx.x >> 3);
  const int e = swzwg >> 6, bm = (swzwg >> 3) & 7, bn = swzwg & 7;

  const char* Bb = (const char*)(W + ((size_t)e * F2 + bn * 256) * KDIM);

  // B staging source coords (linear LDS dest, pre-swizzled global source)
  const int L0 = wv * 1024 + lane * 16;
  const int lin0 = L0 ^ (((L0 >> 7) & 7) << 4);
  const int srow0 = lin0 >> 7, scolb = lin0 & 127;

  // A staging: pass p owns row p*64 + (tid>>3), lanes 0-7 cover the row's
  // 256B k-slice (2 float4 each).
  const int arow_loc = tid >> 3;
  const int k0 = (tid & 7) * 8;
  const float* Arow[4];
  int AwOff[4];
#pragma unroll
  for (int p = 0; p < 4; ++p) {
    int row = p * 64 + arow_loc;
    int tok = sidx[e * CHUNK + bm * 256 + row];
    Arow[p] = hidden + (size_t)tok * H_DIM + k0;
    AwOff[p] = (row >> 7) * 16384 + ((row & 127) << 7) + ((k0 * 2) ^ ((row & 7) << 4));
  }

  const int rA = lane & 15;
  const int swzr = (rA & 7) << 4;
  const int cb = (lane >> 4) * 16;

  f32x4 acc[8][4] = {};
  float4 al[4];  // one A-half (2 rows x 32B) in flight

  auto issueB = [&](int buf, int kt) {
#pragma unroll
    for (int half = 0; half < 2; ++half) {
      char* ld = smem + buf * 65536 + 32768 + half * 16384 + wv * 1024;
      size_t rb = (size_t)(half * 128 + srow0) * (KDIM * 2) + (size_t)kt * 128 + scolb;
      gload_lds16(Bb + rb, ld);
      gload_lds16(Bb + rb + (size_t)64 * (KDIM * 2), ld + 8192);
    }
  };
  auto issueA = [&](int h, int kt) {
#pragma unroll
    for (int q = 0; q < 2; ++q) {
      const float* s = Arow[h * 2 + q] + kt * 64;
      al[q * 2] = *(const float4*)s;
      al[q * 2 + 1] = *(const float4*)(s + 4);
    }
  };
  auto writeA = [&](int buf, int h) {
#pragma unroll
    for (int q = 0; q < 2; ++q) {
      float4 u0 = al[q * 2], u1 = al[q * 2 + 1];
      bf16x8 tv;
      tv[0] = (bf16)u0.x; tv[1] = (bf16)u0.y; tv[2] = (bf16)u0.z; tv[3] = (bf16)u0.w;
      tv[4] = (bf16)u1.x; tv[5] = (bf16)u1.y; tv[6] = (bf16)u1.z; tv[7] = (bf16)u1.w;
      *(bf16x8*)(smem + buf * 65536 + AwOff[h * 2 + q]) = tv;
    }
  };
  auto ldA = [&](int buf, int mi, int ks) {
    int lin = ((mi * 16 + rA) << 7) + ks * 64 + cb;
    return *(const bf16x8*)(smem + buf * 65536 + wm * 16384 + (lin ^ swzr));
  };
  auto ldB = [&](int buf, int ni, int ks) {
    int lin = (((wn & 1) * 64 + ni * 16 + rA) << 7) + ks * 64 + cb;
    return *(const bf16x8*)(smem + buf * 65536 + 32768 + (wn >> 1) * 16384 + (lin ^ swzr));
  };

  // prologue: B(0),B(1) issued; A(0) loaded+written (drains all B(0..1));
  // then LGKM0+BAR publishes tile0.
  issueB(0, 0);
  issueB(1, 1);
  issueA(0, 0);
  writeA(0, 0);
  issueA(1, 0);
  writeA(0, 1);
  LGKM0();
  BAR();

  auto ktile = [&](int t, int cur) {
    const int nxt = cur ^ 1;
    bf16x8 AA[4][2], B0[2][2], B1[2][2];
    // ---- P0: issue A-h0(t+1); frags A0(8)+B0(4); MFMA q0 ----
    if (t + 1 < NT) issueA(0, t + 1);
#pragma unroll
    for (int mi = 0; mi < 4; ++mi) {
      AA[mi][0] = ldA(cur, mi, 0);
      AA[mi][1] = ldA(cur, mi, 1);
    }
#pragma unroll
    for (int ni = 0; ni < 2; ++ni) {
      B0[ni][0] = ldB(cur, ni, 0);
      B0[ni][1] = ldB(cur, ni, 1);
    }
    LGKM8();
    BAR();
    LGKM0();
    SCHED0();
    PRIO(1);
#pragma unroll
    for (int mi = 0; mi < 4; ++mi)
#pragma unroll
      for (int ni = 0; ni < 2; ++ni) {
        acc[mi][ni] = MF(AA[mi][0], B0[ni][0], acc[mi][ni]);
        acc[mi][ni] = MF(AA[mi][1], B0[ni][1], acc[mi][ni]);
      }
    PRIO(0);
    BAR();
    // ---- P1: frags B1(4); MFMA q1 ----
#pragma unroll
    for (int ni = 0; ni < 2; ++ni) {
      B1[ni][0] = ldB(cur, 2 + ni, 0);
      B1[ni][1] = ldB(cur, 2 + ni, 1);
    }
    BAR();
    LGKM0();
    SCHED0();
    PRIO(1);
#pragma unroll
    for (int mi = 0; mi < 4; ++mi)
#pragma unroll
      for (int ni = 0; ni < 2; ++ni) {
        acc[mi][2 + ni] = MF(AA[mi][0], B1[ni][0], acc[mi][2 + ni]);
        acc[mi][2 + ni] = MF(AA[mi][1], B1[ni][1], acc[mi][2 + ni]);
      }
    PRIO(0);
    BAR();
    // ---- P2: frags A1(8); writeA h0 -> nxt; issue A-h1(t+1); MFMA q2 ----
#pragma unroll
    for (int mi = 0; mi < 4; ++mi) {
      AA[mi][0] = ldA(cur, 4 + mi, 0);
      AA[mi][1] = ldA(cur, 4 + mi, 1);
    }
    if (t + 1 < NT) {
      writeA(nxt, 0);
      issueA(1, t + 1);
    }
    BAR();
    LGKM0();
    SCHED0();
    PRIO(1);
#pragma unroll
    for (int mi = 0; mi < 4; ++mi)
#pragma unroll
      for (int ni = 0; ni < 2; ++ni) {
        acc[4 + mi][ni] = MF(AA[mi][0], B0[ni][0], acc[4 + mi][ni]);
        acc[4 + mi][ni] = MF(AA[mi][1], B0[ni][1], acc[4 + mi][ni]);
      }
    PRIO(0);
    BAR();
    // ---- P3: writeA h1 -> nxt (drains B(t+1)); issue B(t+2); MFMA q3 ----
    if (t + 1 < NT) writeA(nxt, 1);
    if (t + 2 < NT) issueB(cur, t + 2);
    LGKM0();
    BAR();
    PRIO(1);
#pragma unroll
    for (int mi = 0; mi < 4; ++mi)
#pragma unroll
      for (int ni = 0; ni < 2; ++ni) {
        acc[4 + mi][2 + ni] = MF(AA[mi][0], B1[ni][0], acc[4 + mi][2 + ni]);
        acc[4 + mi][2 + ni] = MF(AA[mi][1], B1[ni][1], acc[4 + mi][2 + ni]);
      }
    PRIO(0);
    BAR();
  };

  for (int tt = 0; tt < NT; tt += 2) {
    ktile(tt, 0);
    ktile(tt + 1, 1);
  }

  // ---- epilogue: silu(gate)*up; fragment pairs (2p,2p+1)=(gate,up) ----
  bf16* actp = act + ((size_t)e * CHUNK + bm * 256 + wm * 128) * IPE;
  const int r0 = (lane >> 4) * 4;
  const int c0 = bn * 128 + wn * 32 + (lane & 15);
#pragma unroll
  for (int mi = 0; mi < 8; ++mi)
#pragma unroll
    for (int p = 0; p < 2; ++p) {
      f32x4 g = acc[mi][2 * p], u = acc[mi][2 * p + 1];
#pragma unroll
      for (int r = 0; r < 4; ++r) {
        float gv = g[r];
        float a = gv / (1.f + __expf(-gv)) * u[r];
        actp[(size_t)(mi * 16 + r0 + r) * IPE + c0 + p * 16] = (bf16)a;
      }
    }
}

// ---------------------------------------------------------------------------
// GEMM2 (R5 structure, unchanged): act x w2t -> scatter fp32 rows.
// ---------------------------------------------------------------------------
__global__ __launch_bounds__(512, 2) void k_gemm2(
    const bf16* __restrict__ Aptr, const bf16* __restrict__ Bptr,
    const int* __restrict__ sidx, float* __restrict__ fout) {
  extern __shared__ char smem[];
  const int tid = threadIdx.x, lane = tid & 63, wv = tid >> 6;
  const int wm = wv >> 2, wn = wv & 3;
  constexpr int KDIM = IPE;
  constexpr int NT = KDIM / 64;  // 16

  int swzwg = (blockIdx.x & 7) * (gridDim.x >> 3) + (blockIdx.x >> 3);
  const int e = swzwg >> 6, bm = (swzwg >> 3) & 7, bn = swzwg & 7;

  const char* Ab = (const char*)(Aptr + ((size_t)e * CHUNK + bm * 256) * KDIM);
  const char* Bb = (const char*)(Bptr + ((size_t)e * 2048 + bn * 256) * KDIM);

  const int L0 = wv * 1024 + lane * 16;
  const int lin0 = L0 ^ (((L0 >> 7) & 7) << 4);
  const int srow0 = lin0 >> 7, scolb = lin0 & 127;

  const int rA = lane & 15;
  const int swzr = (rA & 7) << 4;
  const int cb = (lane >> 4) * 16;

  f32x4 acc[8][4] = {};

  auto stage = [&](int buf, int mat, int half, int kt) {
    const char* gb = (mat == 0) ? Ab : Bb;
    char* ld = smem + buf * 65536 + mat * 32768 + half * 16384 + wv * 1024;
    size_t rb = (size_t)(half * 128 + srow0) * (KDIM * 2) + (size_t)kt * 128 + scolb;
    gload_lds16(gb + rb, ld);
    gload_lds16(gb + rb + (size_t)64 * (KDIM * 2), ld + 8192);
  };
  auto ldA = [&](int buf, int mi, int ks) {
    int lin = ((mi * 16 + rA) << 7) + ks * 64 + cb;
    return *(const bf16x8*)(smem + buf * 65536 + wm * 16384 + (lin ^ swzr));
  };
  auto ldB = [&](int buf, int ni, int ks) {
    int lin = (((wn & 1) * 64 + ni * 16 + rA) << 7) + ks * 64 + cb;
    return *(const bf16x8*)(smem + buf * 65536 + 32768 + (wn >> 1) * 16384 + (lin ^ swzr));
  };

  stage(0, 1, 0, 0); stage(0, 1, 1, 0); stage(0, 0, 0, 0); stage(0, 0, 1, 0);
  stage(1, 1, 0, 1); stage(1, 1, 1, 1); stage(1, 0, 0, 1);
  VM6();
  BAR();

  auto ktile = [&](int t, int cur) {
    const int nxt = cur ^ 1;
    bf16x8 AA[4][2], B0[2][2], B1[2][2];
#pragma unroll
    for (int mi = 0; mi < 4; ++mi) {
      AA[mi][0] = ldA(cur, mi, 0);
      AA[mi][1] = ldA(cur, mi, 1);
    }
#pragma unroll
    for (int ni = 0; ni < 2; ++ni) {
      B0[ni][0] = ldB(cur, ni, 0);
      B0[ni][1] = ldB(cur, ni, 1);
    }
    if (t + 1 < NT) stage(nxt, 0, 1, t + 1);
    LGKM8();
    BAR();
    LGKM0();
    SCHED0();
    PRIO(1);
#pragma unroll
    for (int mi = 0; mi < 4; ++mi)
#pragma unroll
      for (int ni = 0; ni < 2; ++ni) {
        acc[mi][ni] = MF(AA[mi][0], B0[ni][0], acc[mi][ni]);
        acc[mi][ni] = MF(AA[mi][1], B0[ni][1], acc[mi][ni]);
      }
    PRIO(0);
    BAR();
#pragma unroll
    for (int ni = 0; ni < 2; ++ni) {
      B1[ni][0] = ldB(cur, 2 + ni, 0);
      B1[ni][1] = ldB(cur, 2 + ni, 1);
    }
    if (t + 2 < NT) stage(cur, 1, 0, t + 2);
    BAR();
    LGKM0();
    SCHED0();
    PRIO(1);
#pragma unroll
    for (int mi = 0; mi < 4; ++mi)
#pragma unroll
      for (int ni = 0; ni < 2; ++ni) {
        acc[mi][2 + ni] = MF(AA[mi][0], B1[ni][0], acc[mi][2 + ni]);
        acc[mi][2 + ni] = MF(AA[mi][1], B1[ni][1], acc[mi][2 + ni]);
      }
    PRIO(0);
    BAR();
#pragma unroll
    for (int mi = 0; mi < 4; ++mi) {
      AA[mi][0] = ldA(cur, 4 + mi, 0);
      AA[mi][1] = ldA(cur, 4 + mi, 1);
    }
    if (t + 2 < NT) stage(cur, 1, 1, t + 2);
    BAR();
    LGKM0();
    SCHED0();
    PRIO(1);
#pragma unroll
    for (int mi = 0; mi < 4; ++mi)
#pragma unroll
      for (int ni = 0; ni < 2; ++ni) {
        acc[4 + mi][ni] = MF(AA[mi][0], B0[ni][0], acc[4 + mi][ni]);
        acc[4 + mi][ni] = MF(AA[mi][1], B0[ni][1], acc[4 + mi][ni]);
      }
    PRIO(0);
    BAR();
    if (t + 2 < NT) {
      stage(cur, 0, 0, t + 2);
      VM6();
    } else if (t + 1 < NT) {
      VM0();
    }
    BAR();
    PRIO(1);
#pragma unroll
    for (int mi = 0; mi < 4; ++mi)
#pragma unroll
      for (int ni = 0; ni < 2; ++ni) {
        acc[4 + mi][2 + ni] = MF(AA[mi][0], B1[ni][0], acc[4 + mi][2 + ni]);
        acc[4 + mi][2 + ni] = MF(AA[mi][1], B1[ni][1], acc[4 + mi][2 + ni]);
      }
    PRIO(0);
    BAR();
  };

  for (int tt = 0; tt < NT; tt += 2) {
    ktile(tt, 0);
    ktile(tt + 1, 1);
  }

  const int* sp = sidx + e * CHUNK + bm * 256 + wm * 128;
  const int r0 = (lane >> 4) * 4;
  const int c0 = bn * 256 + wn * 64 + (lane & 15);
#pragma unroll
  for (int mi = 0; mi < 8; ++mi)
#pragma unroll
    for (int r = 0; r < 4; ++r) {
      int dst = sp[mi * 16 + r0 + r];
      float* op = fout + (size_t)dst * H_DIM + c0;
#pragma unroll
      for (int ni = 0; ni < 4; ++ni) op[ni * 16] = acc[mi][ni][r];
    }
}

// ---------------------------------------------------------------------------
extern "C" void kernel_launch(void* const* d_in, const int* in_sizes, int n_in,
                              void* d_out, int out_size, void* d_ws, size_t ws_size,
                              hipStream_t stream) {
  const float* hidden = (const float*)d_in[0];
  const int* sidx = (const int*)d_in[1];
  const float* w1 = (const float*)d_in[2];
  const float* w2 = (const float*)d_in[3];
  float* out = (float*)d_out;

  // Workspace (peak 128 MiB): w1t [0,64M), w2t [64,96M), act [96,128M)
  char* ws = (char*)d_ws;
  bf16* w1t = (bf16*)(ws);
  bf16* w2t = (bf16*)(ws + (size_t)67108864);
  bf16* act = (bf16*)(ws + (size_t)100663296);

  hipFuncSetAttribute((const void*)k_gemm1f,
                      hipFuncAttributeMaxDynamicSharedMemorySize, 131072);
  hipFuncSetAttribute((const void*)k_gemm2,
                      hipFuncAttributeMaxDynamicSharedMemorySize, 131072);

  k_tr_w1<<<dim3(32, 32, NE), 256, 0, stream>>>(w1, w1t);
  k_tr_w2<<<dim3(32, 16, NE), 256, 0, stream>>>(w2, w2t);
  k_gemm1f<<<dim3(512), 512, 131072, stream>>>(hidden, sidx, w1t, act);
  k_gemm2<<<dim3(512), 512, 131072, stream>>>(act, w2t, sidx, out);
}

// Round 8
// 380.229 us; speedup vs baseline: 3.0833x; 1.1193x over previous
//
#include <hip/hip_runtime.h>
#include <hip/hip_bf16.h>

#define N_TOK 16384
#define H_DIM 2048
#define NE 8
#define CHUNK 2048
#define IPE 1024
#define F2 2048

typedef __bf16 bf16;
typedef bf16 bf16x8 __attribute__((ext_vector_type(8)));
typedef float f32x4 __attribute__((ext_vector_type(4)));

typedef __attribute__((address_space(1))) void gvoid;
typedef __attribute__((address_space(3))) void svoid;

__device__ __forceinline__ void gload_lds16(const void* g, void* l) {
  __builtin_amdgcn_global_load_lds((gvoid*)g, (svoid*)l, 16, 0, 0);
}
__device__ __forceinline__ f32x4 MF(bf16x8 a, bf16x8 b, f32x4 c) {
  return __builtin_amdgcn_mfma_f32_16x16x32_bf16(a, b, c, 0, 0, 0);
}
// LDS logical<->physical involution (constant over any 16B-aligned chunk)
__device__ __forceinline__ int swz(int x) { return x ^ (((x >> 7) & 7) << 4); }

// ---------------------------------------------------------------------------
// Merged prep: blocks [0,8192) = tr_w1 (gate/up-interleaved transpose),
// blocks [8192,12288) = tr_w2 (plain transpose). 256 thr, wide bf16x8 stores.
// ---------------------------------------------------------------------------
__global__ __launch_bounds__(256) void k_prep(const float* __restrict__ w1,
                                              const float* __restrict__ w2,
                                              bf16* __restrict__ w1t,
                                              bf16* __restrict__ w2t) {
  __shared__ bf16 lds[64][68];
  int b = blockIdx.x;
  int tx = threadIdx.x & 63, ty = threadIdx.x >> 6;
  if (b < 8192) {
    int fB = b & 31, hB = (b >> 5) & 31, e = b >> 10;
    const float* ip = w1 + ((size_t)e * H_DIM + hB * 64) * F2;
    int scol = (tx < 32) ? (fB * 32 + tx) : (1024 + fB * 32 + (tx - 32));
#pragma unroll
    for (int p = 0; p < 16; ++p) {
      int hl = p * 4 + ty;
      lds[hl][tx] = (bf16)ip[(size_t)hl * F2 + scol];
    }
    __syncthreads();
    int fl = threadIdx.x >> 2, hseg = (threadIdx.x & 3) * 16;
    int g = fl >> 4, w = fl & 15;
    int lcol = ((g >> 1) << 4) + w + ((g & 1) << 5);
    bf16 v[16];
#pragma unroll
    for (int j = 0; j < 16; ++j) v[j] = lds[hseg + j][lcol];
    bf16* op = w1t + ((size_t)e * F2 + fB * 64 + fl) * H_DIM + hB * 64 + hseg;
    *(bf16x8*)op = *(bf16x8*)&v[0];
    *(bf16x8*)(op + 8) = *(bf16x8*)&v[8];
  } else {
    int i2 = b - 8192;
    int hB = i2 & 31, iB = (i2 >> 5) & 15, e = i2 >> 9;
    const float* ip = w2 + (size_t)e * IPE * H_DIM + (size_t)iB * 64 * H_DIM + hB * 64;
#pragma unroll
    for (int p = 0; p < 16; ++p) {
      int il = p * 4 + ty;
      lds[il][tx] = (bf16)ip[(size_t)il * H_DIM + tx];
    }
    __syncthreads();
    int hl = threadIdx.x >> 2, iseg = (threadIdx.x & 3) * 16;
    bf16 v[16];
#pragma unroll
    for (int j = 0; j < 16; ++j) v[j] = lds[iseg + j][hl];
    bf16* op = w2t + ((size_t)e * H_DIM + hB * 64 + hl) * IPE + iB * 64 + iseg;
    *(bf16x8*)op = *(bf16x8*)&v[0];
    *(bf16x8*)(op + 8) = *(bf16x8*)&v[8];
  }
}

// ---------------------------------------------------------------------------
// 256x128xBK32 grouped GEMM, 8 waves (2M x 4N), 48 KiB LDS -> 2 blocks/CU
// (cross-block MFMA/LDS overlap, m114 mechanism). T3-minimum loop: one
// __syncthreads per K-tile (full drain; safe with reg-staged A by design).
//
// LDS (per buf 24576B): A [0,16K): 256 rows x 32k bf16 packed 2 rows/128B;
// B [16K,24K): 128 rows x 32k. All accesses through swz() involution.
//
// FUSED_A (GEMM1): A = hidden fp32 rows gathered via sidx; thread owns
//   (row=tid>>1, khalf=tid&1): 4x float4 coalesced -> cvt -> 2 ds_write_b128.
// else (GEMM2): A = act bf16 via gload_lds (2/thread, pre-swizzled source).
// B: always bf16 (w1t/w2t) via gload_lds (1/thread).
// SILU: gate/up fragment pair (ni0,ni1) -> act; else scatter fp32 via sidx.
// ---------------------------------------------------------------------------
template <int KDIM, bool FUSED_A, bool SILU>
__global__ __launch_bounds__(512, 4) void k_gemm(
    const void* __restrict__ Asrc, const bf16* __restrict__ Bptr,
    const int* __restrict__ sidx, bf16* __restrict__ act,
    float* __restrict__ fout) {
  __shared__ char smem[49152];
  const int tid = threadIdx.x, lane = tid & 63, wv = tid >> 6;
  const int wm = wv >> 2, wn = wv & 3;
  constexpr int NT = KDIM / 32;

  // XCD swizzle, 1024 blocks (%8==0 bijective)
  const int bid = blockIdx.x;
  const int swg = (bid & 7) * 128 + (bid >> 3);
  const int e = swg >> 7, bm = (swg >> 4) & 7, bn = swg & 15;

  // ---- B staging: 1 gload16/thread; linear dest, inverse-swz source ----
  const int PB = tid * 16;
  const int LB = swz(PB);
  const char* Bsrc = (const char*)Bptr +
      ((size_t)e * 2048 + bn * 128 + (LB >> 6)) * (KDIM * 2) + (LB & 63);

  // ---- A staging ----
  const int aR = tid >> 1, akh = tid & 1;
  const float* Afp = nullptr;
  int AwP0 = 0, AwP1 = 0;
  const char* Ag0 = nullptr;
  const char* Ag1 = nullptr;
  int AgP0 = 0, AgP1 = 0;
  if constexpr (FUSED_A) {
    int tok = sidx[e * CHUNK + bm * 256 + aR];
    Afp = (const float*)Asrc + (size_t)tok * H_DIM + akh * 16;
    int L0 = (aR >> 1) * 128 + (aR & 1) * 64 + akh * 32;
    AwP0 = swz(L0);
    AwP1 = swz(L0 + 16);
  } else {
    AgP0 = wv * 2048 + lane * 16;
    AgP1 = AgP0 + 1024;
    int L0 = swz(AgP0), L1 = swz(AgP1);
    Ag0 = (const char*)Asrc +
        ((size_t)e * CHUNK + bm * 256 + (L0 >> 6)) * (KDIM * 2) + (L0 & 63);
    Ag1 = (const char*)Asrc +
        ((size_t)e * CHUNK + bm * 256 + (L1 >> 6)) * (KDIM * 2) + (L1 & 63);
  }

  const int rA = lane & 15;
  const int cb = (lane >> 4) * 16;

  f32x4 acc[8][2] = {};
  float4 al0, al1, al2, al3;

  auto loadA = [&](int kt) {
    const float* s = Afp + kt * 32;
    al0 = *(const float4*)s;
    al1 = *(const float4*)(s + 4);
    al2 = *(const float4*)(s + 8);
    al3 = *(const float4*)(s + 12);
  };
  auto writeA = [&](int buf) {
    bf16x8 t0, t1;
    t0[0] = (bf16)al0.x; t0[1] = (bf16)al0.y; t0[2] = (bf16)al0.z; t0[3] = (bf16)al0.w;
    t0[4] = (bf16)al1.x; t0[5] = (bf16)al1.y; t0[6] = (bf16)al1.z; t0[7] = (bf16)al1.w;
    t1[0] = (bf16)al2.x; t1[1] = (bf16)al2.y; t1[2] = (bf16)al2.z; t1[3] = (bf16)al2.w;
    t1[4] = (bf16)al3.x; t1[5] = (bf16)al3.y; t1[6] = (bf16)al3.z; t1[7] = (bf16)al3.w;
    *(bf16x8*)(smem + buf * 24576 + AwP0) = t0;
    *(bf16x8*)(smem + buf * 24576 + AwP1) = t1;
  };
  auto stageA = [&](int buf, int kt) {
    gload_lds16(Ag0 + kt * 64, smem + buf * 24576 + AgP0);
    gload_lds16(Ag1 + kt * 64, smem + buf * 24576 + AgP1);
  };
  auto stageB = [&](int buf, int kt) {
    gload_lds16(Bsrc + kt * 64, smem + buf * 24576 + 16384 + PB);
  };
  auto ldA = [&](int buf, int mi) {
    int R = wm * 128 + mi * 16 + rA;
    int L = (R >> 1) * 128 + (R & 1) * 64 + cb;
    return *(const bf16x8*)(smem + buf * 24576 + swz(L));
  };
  auto ldB = [&](int buf, int ni) {
    int f = wn * 32 + ni * 16 + rA;
    int L = (f >> 1) * 128 + (f & 1) * 64 + cb;
    return *(const bf16x8*)(smem + buf * 24576 + 16384 + swz(L));
  };

  // ---- prologue: tile 0 into buf 0 ----
  if constexpr (FUSED_A) {
    loadA(0);
    stageB(0, 0);
    writeA(0);
  } else {
    stageA(0, 0);
    stageB(0, 0);
  }
  __syncthreads();

  for (int t = 0; t < NT; ++t) {
    const int cur = t & 1, nxt = cur ^ 1;
    if (t + 1 < NT) {
      if constexpr (FUSED_A) {
        loadA(t + 1);        // issue A reg-loads first (oldest)
        stageB(nxt, t + 1);  // B gload younger: writeA's wait won't drain it
      } else {
        stageA(nxt, t + 1);
        stageB(nxt, t + 1);
      }
    }
    bf16x8 B0 = ldB(cur, 0), B1 = ldB(cur, 1);
    {
      bf16x8 A0 = ldA(cur, 0), A1 = ldA(cur, 1), A2 = ldA(cur, 2), A3 = ldA(cur, 3);
      acc[0][0] = MF(A0, B0, acc[0][0]); acc[0][1] = MF(A0, B1, acc[0][1]);
      acc[1][0] = MF(A1, B0, acc[1][0]); acc[1][1] = MF(A1, B1, acc[1][1]);
      acc[2][0] = MF(A2, B0, acc[2][0]); acc[2][1] = MF(A2, B1, acc[2][1]);
      acc[3][0] = MF(A3, B0, acc[3][0]); acc[3][1] = MF(A3, B1, acc[3][1]);
    }
    {
      bf16x8 A4 = ldA(cur, 4), A5 = ldA(cur, 5), A6 = ldA(cur, 6), A7 = ldA(cur, 7);
      acc[4][0] = MF(A4, B0, acc[4][0]); acc[4][1] = MF(A4, B1, acc[4][1]);
      acc[5][0] = MF(A5, B0, acc[5][0]); acc[5][1] = MF(A5, B1, acc[5][1]);
      acc[6][0] = MF(A6, B0, acc[6][0]); acc[6][1] = MF(A6, B1, acc[6][1]);
      acc[7][0] = MF(A7, B0, acc[7][0]); acc[7][1] = MF(A7, B1, acc[7][1]);
    }
    if constexpr (FUSED_A) {
      if (t + 1 < NT) writeA(nxt);
    }
    __syncthreads();  // drains vmcnt+lgkm (gloads landed), publishes nxt
  }

  if constexpr (SILU) {
    // ni0 = gate, ni1 = up (g = bn*8+wn*2+ni even/odd)
    bf16* actp = act + ((size_t)e * CHUNK + bm * 256 + wm * 128) * IPE;
    const int r0 = (lane >> 4) * 4;
    const int c0 = bn * 64 + wn * 16 + rA;
#pragma unroll
    for (int mi = 0; mi < 8; ++mi) {
      f32x4 g = acc[mi][0], u = acc[mi][1];
#pragma unroll
      for (int r = 0; r < 4; ++r) {
        float gv = g[r];
        float a = gv / (1.f + __expf(-gv)) * u[r];
        actp[(size_t)(mi * 16 + r0 + r) * IPE + c0] = (bf16)a;
      }
    }
  } else {
    const int* sp = sidx + e * CHUNK + bm * 256 + wm * 128;
    const int r0 = (lane >> 4) * 4;
    const int c0 = bn * 128 + wn * 32 + rA;
#pragma unroll
    for (int mi = 0; mi < 8; ++mi)
#pragma unroll
      for (int r = 0; r < 4; ++r) {
        int dst = sp[mi * 16 + r0 + r];
        float* op = fout + (size_t)dst * H_DIM + c0;
        op[0] = acc[mi][0][r];
        op[16] = acc[mi][1][r];
      }
  }
}

// ---------------------------------------------------------------------------
extern "C" void kernel_launch(void* const* d_in, const int* in_sizes, int n_in,
                              void* d_out, int out_size, void* d_ws, size_t ws_size,
                              hipStream_t stream) {
  const float* hidden = (const float*)d_in[0];
  const int* sidx = (const int*)d_in[1];
  const float* w1 = (const float*)d_in[2];
  const float* w2 = (const float*)d_in[3];
  float* out = (float*)d_out;

  // Workspace (peak 128 MiB): w1t [0,64M), w2t [64,96M), act [96,128M)
  char* ws = (char*)d_ws;
  bf16* w1t = (bf16*)(ws);
  bf16* w2t = (bf16*)(ws + (size_t)67108864);
  bf16* act = (bf16*)(ws + (size_t)100663296);

  k_prep<<<dim3(12288), 256, 0, stream>>>(w1, w2, w1t, w2t);
  k_gemm<H_DIM, true, true><<<dim3(1024), 512, 0, stream>>>(
      hidden, w1t, sidx, act, nullptr);
  k_gemm<IPE, false, false><<<dim3(1024), 512, 0, stream>>>(
      act, w2t, sidx, nullptr, out);
}

// Round 9
// 302.345 us; speedup vs baseline: 3.8776x; 1.2576x over previous
//
#include <hip/hip_runtime.h>
#include <hip/hip_bf16.h>

#define N_TOK 16384
#define H_DIM 2048
#define NE 8
#define CHUNK 2048
#define IPE 1024
#define F2 2048

typedef __bf16 bf16;
typedef bf16 bf16x8 __attribute__((ext_vector_type(8)));
typedef float f32x4 __attribute__((ext_vector_type(4)));

typedef __attribute__((address_space(1))) void gvoid;
typedef __attribute__((address_space(3))) void svoid;

__device__ __forceinline__ void gload_lds16(const void* g, void* l) {
  __builtin_amdgcn_global_load_lds((gvoid*)g, (svoid*)l, 16, 0, 0);
}
__device__ __forceinline__ f32x4 MF(bf16x8 a, bf16x8 b, f32x4 c) {
  return __builtin_amdgcn_mfma_f32_16x16x32_bf16(a, b, c, 0, 0, 0);
}

#define BAR() __builtin_amdgcn_s_barrier()
#define LGKM0() asm volatile("s_waitcnt lgkmcnt(0)" ::: "memory")
#define LGKM8() asm volatile("s_waitcnt lgkmcnt(8)" ::: "memory")
#define VM6() asm volatile("s_waitcnt vmcnt(6)" ::: "memory")
#define VM0() asm volatile("s_waitcnt vmcnt(0)" ::: "memory")
#define PRIO(x) __builtin_amdgcn_s_setprio(x)
#define SCHED0() __builtin_amdgcn_sched_barrier(0)

// ---------------------------------------------------------------------------
// Merged prep, one launch:
//   blocks [0,16384):        gather+cvt   hidden[sidx[row]] -> xs (bf16)
//   blocks [16384,24576):    tr_w1  w1 [E][H][2I] fp32 -> w1t [E][F'][H] bf16
//                            (16-col gate/up interleave), float4 loads
//   blocks [24576,28672):    tr_w2  w2 [E][I][H] fp32 -> w2t [E][H][I] bf16,
//                            float4 loads
// ---------------------------------------------------------------------------
__global__ __launch_bounds__(256) void k_prep(
    const float* __restrict__ hidden, const int* __restrict__ sidx,
    const float* __restrict__ w1, const float* __restrict__ w2,
    bf16* __restrict__ xs, bf16* __restrict__ w1t, bf16* __restrict__ w2t) {
  int b = blockIdx.x;
  int tid = threadIdx.x;
  if (b < 16384) {
    // ---- gather ----
    int row = b;
    int src = sidx[row];
    const float4* ip = (const float4*)(hidden + (size_t)src * H_DIM);
    float4 f0 = ip[tid * 2], f1 = ip[tid * 2 + 1];
    bf16x8 v;
    v[0] = (bf16)f0.x; v[1] = (bf16)f0.y; v[2] = (bf16)f0.z; v[3] = (bf16)f0.w;
    v[4] = (bf16)f1.x; v[5] = (bf16)f1.y; v[6] = (bf16)f1.z; v[7] = (bf16)f1.w;
    *(bf16x8*)(xs + (size_t)row * H_DIM + tid * 8) = v;
    return;
  }
  __shared__ bf16 lds[64][68];
  if (b < 24576) {
    // ---- tr_w1 ----
    int i1 = b - 16384;
    int fB = i1 & 31, hB = (i1 >> 5) & 31, e = i1 >> 10;
    const float* ip = w1 + ((size_t)e * H_DIM + hB * 64) * F2;
    // load: 1024 float4 units: half(gate/up), row(64), c4(8 per half-row)
#pragma unroll
    for (int p = 0; p < 4; ++p) {
      int idx = p * 256 + tid;
      int half = idx >> 9, rem = idx & 511;
      int row = rem >> 3, c4 = rem & 7;
      float4 v = *(const float4*)(ip + (size_t)row * F2 + half * 1024 + fB * 32 + c4 * 4);
      bf16* d = &lds[row][half * 32 + c4 * 4];
      d[0] = (bf16)v.x; d[1] = (bf16)v.y; d[2] = (bf16)v.z; d[3] = (bf16)v.w;
    }
    __syncthreads();
    // store: thread owns out row f'=fl, 16 h-cols (bf16x8 x2)
    int fl = tid >> 2, hseg = (tid & 3) * 16;
    int g = fl >> 4, w = fl & 15;
    int lcol = ((g >> 1) << 4) + w + ((g & 1) << 5);
    bf16 v[16];
#pragma unroll
    for (int j = 0; j < 16; ++j) v[j] = lds[hseg + j][lcol];
    bf16* op = w1t + ((size_t)e * F2 + fB * 64 + fl) * H_DIM + hB * 64 + hseg;
    *(bf16x8*)op = *(bf16x8*)&v[0];
    *(bf16x8*)(op + 8) = *(bf16x8*)&v[8];
  } else {
    // ---- tr_w2 ----
    int i2 = b - 24576;
    int hB = i2 & 31, iB = (i2 >> 5) & 15, e = i2 >> 9;
    const float* ip = w2 + (size_t)e * IPE * H_DIM + (size_t)iB * 64 * H_DIM + hB * 64;
#pragma unroll
    for (int p = 0; p < 4; ++p) {
      int idx = p * 256 + tid;
      int row = idx >> 4, c4 = idx & 15;
      float4 v = *(const float4*)(ip + (size_t)row * H_DIM + c4 * 4);
      bf16* d = &lds[row][c4 * 4];
      d[0] = (bf16)v.x; d[1] = (bf16)v.y; d[2] = (bf16)v.z; d[3] = (bf16)v.w;
    }
    __syncthreads();
    int hl = tid >> 2, iseg = (tid & 3) * 16;
    bf16 v[16];
#pragma unroll
    for (int j = 0; j < 16; ++j) v[j] = lds[iseg + j][hl];
    bf16* op = w2t + ((size_t)e * H_DIM + hB * 64 + hl) * IPE + iB * 64 + iseg;
    *(bf16x8*)op = *(bf16x8*)&v[0];
    *(bf16x8*)(op + 8) = *(bf16x8*)&v[8];
  }
}

// ---------------------------------------------------------------------------
// 256x256x64 8-phase grouped GEMM (R5 exact — known-good 306 us config).
// ---------------------------------------------------------------------------
template <int KDIM, bool SILU>
__global__ __launch_bounds__(512, 2) void k_gemm8(
    const bf16* __restrict__ Aptr, const bf16* __restrict__ Bptr,
    const int* __restrict__ sidx, bf16* __restrict__ act,
    float* __restrict__ fout) {
  extern __shared__ char smem[];
  const int tid = threadIdx.x, lane = tid & 63, wv = tid >> 6;
  const int wm = wv >> 2, wn = wv & 3;
  constexpr int NT = KDIM / 64;

  int swzwg = (blockIdx.x & 7) * (gridDim.x >> 3) + (blockIdx.x >> 3);
  const int e = swzwg >> 6, bm = (swzwg >> 3) & 7, bn = swzwg & 7;

  const char* Ab = (const char*)(Aptr + ((size_t)e * CHUNK + bm * 256) * KDIM);
  const char* Bb = (const char*)(Bptr + ((size_t)e * 2048 + bn * 256) * KDIM);

  const int L0 = wv * 1024 + lane * 16;
  const int lin0 = L0 ^ (((L0 >> 7) & 7) << 4);
  const int srow0 = lin0 >> 7, scolb = lin0 & 127;

  const int rA = lane & 15;
  const int swzr = (rA & 7) << 4;
  const int cb = (lane >> 4) * 16;

  f32x4 acc[8][4] = {};

  auto stage = [&](int buf, int mat, int half, int kt) {
    const char* gb = (mat == 0) ? Ab : Bb;
    char* ld = smem + buf * 65536 + mat * 32768 + half * 16384 + wv * 1024;
    size_t rb = (size_t)(half * 128 + srow0) * (KDIM * 2) + (size_t)kt * 128 + scolb;
    gload_lds16(gb + rb, ld);
    gload_lds16(gb + rb + (size_t)64 * (KDIM * 2), ld + 8192);
  };
  auto ldA = [&](int buf, int mi, int ks) {
    int lin = ((mi * 16 + rA) << 7) + ks * 64 + cb;
    return *(const bf16x8*)(smem + buf * 65536 + wm * 16384 + (lin ^ swzr));
  };
  auto ldB = [&](int buf, int ni, int ks) {
    int lin = (((wn & 1) * 64 + ni * 16 + rA) << 7) + ks * 64 + cb;
    return *(const bf16x8*)(smem + buf * 65536 + 32768 + (wn >> 1) * 16384 + (lin ^ swzr));
  };

  stage(0, 1, 0, 0); stage(0, 1, 1, 0); stage(0, 0, 0, 0); stage(0, 0, 1, 0);
  stage(1, 1, 0, 1); stage(1, 1, 1, 1); stage(1, 0, 0, 1);
  VM6();
  BAR();

  auto ktile = [&](int t, int cur) {
    const int nxt = cur ^ 1;
    bf16x8 AA[4][2], B0[2][2], B1[2][2];
    // ---- P0: read A0(8)+B0(4); stage t+1.A1; MFMA mi0-3 x ni0-1 ----
#pragma unroll
    for (int mi = 0; mi < 4; ++mi) {
      AA[mi][0] = ldA(cur, mi, 0);
      AA[mi][1] = ldA(cur, mi, 1);
    }
#pragma unroll
    for (int ni = 0; ni < 2; ++ni) {
      B0[ni][0] = ldB(cur, ni, 0);
      B0[ni][1] = ldB(cur, ni, 1);
    }
    if (t + 1 < NT) stage(nxt, 0, 1, t + 1);
    LGKM8();
    BAR();
    LGKM0();
    SCHED0();
    PRIO(1);
#pragma unroll
    for (int mi = 0; mi < 4; ++mi)
#pragma unroll
      for (int ni = 0; ni < 2; ++ni) {
        acc[mi][ni] = MF(AA[mi][0], B0[ni][0], acc[mi][ni]);
        acc[mi][ni] = MF(AA[mi][1], B0[ni][1], acc[mi][ni]);
      }
    PRIO(0);
    BAR();
    // ---- P1: read B1(4); stage t+2.B0; MFMA mi0-3 x ni2-3 ----
#pragma unroll
    for (int ni = 0; ni < 2; ++ni) {
      B1[ni][0] = ldB(cur, 2 + ni, 0);
      B1[ni][1] = ldB(cur, 2 + ni, 1);
    }
    if (t + 2 < NT) stage(cur, 1, 0, t + 2);
    BAR();
    LGKM0();
    SCHED0();
    PRIO(1);
#pragma unroll
    for (int mi = 0; mi < 4; ++mi)
#pragma unroll
      for (int ni = 0; ni < 2; ++ni) {
        acc[mi][2 + ni] = MF(AA[mi][0], B1[ni][0], acc[mi][2 + ni]);
        acc[mi][2 + ni] = MF(AA[mi][1], B1[ni][1], acc[mi][2 + ni]);
      }
    PRIO(0);
    BAR();
    // ---- P2: read A1(8) (aliased); stage t+2.B1; MFMA mi4-7 x ni0-1 ----
#pragma unroll
    for (int mi = 0; mi < 4; ++mi) {
      AA[mi][0] = ldA(cur, 4 + mi, 0);
      AA[mi][1] = ldA(cur, 4 + mi, 1);
    }
    if (t + 2 < NT) stage(cur, 1, 1, t + 2);
    BAR();
    LGKM0();
    SCHED0();
    PRIO(1);
#pragma unroll
    for (int mi = 0; mi < 4; ++mi)
#pragma unroll
      for (int ni = 0; ni < 2; ++ni) {
        acc[4 + mi][ni] = MF(AA[mi][0], B0[ni][0], acc[4 + mi][ni]);
        acc[4 + mi][ni] = MF(AA[mi][1], B0[ni][1], acc[4 + mi][ni]);
      }
    PRIO(0);
    BAR();
    // ---- P3: stage t+2.A0 + vmcnt(6); MFMA mi4-7 x ni2-3 ----
    if (t + 2 < NT) {
      stage(cur, 0, 0, t + 2);
      VM6();
    } else if (t + 1 < NT) {
      VM0();
    }
    BAR();
    PRIO(1);
#pragma unroll
    for (int mi = 0; mi < 4; ++mi)
#pragma unroll
      for (int ni = 0; ni < 2; ++ni) {
        acc[4 + mi][2 + ni] = MF(AA[mi][0], B1[ni][0], acc[4 + mi][2 + ni]);
        acc[4 + mi][2 + ni] = MF(AA[mi][1], B1[ni][1], acc[4 + mi][2 + ni]);
      }
    PRIO(0);
    BAR();
  };

  for (int tt = 0; tt < NT; tt += 2) {
    ktile(tt, 0);
    ktile(tt + 1, 1);
  }

  if constexpr (SILU) {
    bf16* actp = act + ((size_t)e * CHUNK + bm * 256 + wm * 128) * IPE;
    const int r0 = (lane >> 4) * 4;
    const int c0 = bn * 128 + wn * 32 + (lane & 15);
#pragma unroll
    for (int mi = 0; mi < 8; ++mi)
#pragma unroll
      for (int p = 0; p < 2; ++p) {
        f32x4 g = acc[mi][2 * p], u = acc[mi][2 * p + 1];
#pragma unroll
        for (int r = 0; r < 4; ++r) {
          float gv = g[r];
          float a = gv / (1.f + __expf(-gv)) * u[r];
          actp[(size_t)(mi * 16 + r0 + r) * IPE + c0 + p * 16] = (bf16)a;
        }
      }
  } else {
    const int* sp = sidx + e * CHUNK + bm * 256 + wm * 128;
    const int r0 = (lane >> 4) * 4;
    const int c0 = bn * 256 + wn * 64 + (lane & 15);
#pragma unroll
    for (int mi = 0; mi < 8; ++mi)
#pragma unroll
      for (int r = 0; r < 4; ++r) {
        int dst = sp[mi * 16 + r0 + r];
        float* op = fout + (size_t)dst * H_DIM + c0;
#pragma unroll
        for (int ni = 0; ni < 4; ++ni) op[ni * 16] = acc[mi][ni][r];
      }
  }
}

// ---------------------------------------------------------------------------
extern "C" void kernel_launch(void* const* d_in, const int* in_sizes, int n_in,
                              void* d_out, int out_size, void* d_ws, size_t ws_size,
                              hipStream_t stream) {
  const float* hidden = (const float*)d_in[0];
  const int* sidx = (const int*)d_in[1];
  const float* w1 = (const float*)d_in[2];
  const float* w2 = (const float*)d_in[3];
  float* out = (float*)d_out;

  // Workspace (192 MiB, all disjoint — prep runs before both GEMMs):
  //   xs [0,64M), w1t [64,128M), w2t [128,160M), act [160,192M)
  char* ws = (char*)d_ws;
  bf16* xs  = (bf16*)(ws);
  bf16* w1t = (bf16*)(ws + (size_t)67108864);
  bf16* w2t = (bf16*)(ws + (size_t)134217728);
  bf16* act = (bf16*)(ws + (size_t)167772160);

  hipFuncSetAttribute((const void*)k_gemm8<H_DIM, true>,
                      hipFuncAttributeMaxDynamicSharedMemorySize, 131072);
  hipFuncSetAttribute((const void*)k_gemm8<IPE, false>,
                      hipFuncAttributeMaxDynamicSharedMemorySize, 131072);

  k_prep<<<dim3(28672), 256, 0, stream>>>(hidden, sidx, w1, w2, xs, w1t, w2t);
  k_gemm8<H_DIM, true><<<dim3(512), 512, 131072, stream>>>(xs, w1t, nullptr, act, nullptr);
  k_gemm8<IPE, false><<<dim3(512), 512, 131072, stream>>>(act, w2t, sidx, nullptr, out);
}